// Round 1
// baseline (340.969 us; speedup 1.0000x reference)
//
#include <hip/hip_runtime.h>
#include <cstdint>
#include <cstddef>

#define Bb   2
#define Nn   1024
#define Hh   8
#define DHh  64
#define DMm  512
#define TOPK 102   // int(1024 * (1.0 - 0.9)) == 102

// ---------------------------------------------------------------------------
// C[M,N] = A[M,K] @ B[N,K]^T   (both row-major, inner dim K) — f32 vector FMA
// 64x64 tile, BK=16, 256 threads, 4x4 micro-tile per thread.
// ---------------------------------------------------------------------------
__global__ __launch_bounds__(256) void gemm_nt64(
    const float* __restrict__ A, const float* __restrict__ Bm,
    float* __restrict__ C, int M, int N, int K) {
  __shared__ float As[64][17];
  __shared__ float Bs[64][17];
  const int tid = threadIdx.x;
  const int tx  = tid & 15;
  const int ty  = tid >> 4;
  const int bm  = blockIdx.x << 6;
  const int bn  = blockIdx.y << 6;
  float acc[4][4] = {};
  for (int k0 = 0; k0 < K; k0 += 16) {
#pragma unroll
    for (int i = 0; i < 4; ++i) {
      int e = tid + (i << 8);          // 0..1023
      int r = e >> 4, c = e & 15;
      As[r][c] = A[(size_t)(bm + r) * K + k0 + c];
      Bs[r][c] = Bm[(size_t)(bn + r) * K + k0 + c];
    }
    __syncthreads();
#pragma unroll
    for (int kk = 0; kk < 16; ++kk) {
      float a0 = As[(ty << 2) + 0][kk], a1 = As[(ty << 2) + 1][kk];
      float a2 = As[(ty << 2) + 2][kk], a3 = As[(ty << 2) + 3][kk];
      float b0 = Bs[(tx << 2) + 0][kk], b1 = Bs[(tx << 2) + 1][kk];
      float b2 = Bs[(tx << 2) + 2][kk], b3 = Bs[(tx << 2) + 3][kk];
      acc[0][0] = fmaf(a0, b0, acc[0][0]); acc[0][1] = fmaf(a0, b1, acc[0][1]);
      acc[0][2] = fmaf(a0, b2, acc[0][2]); acc[0][3] = fmaf(a0, b3, acc[0][3]);
      acc[1][0] = fmaf(a1, b0, acc[1][0]); acc[1][1] = fmaf(a1, b1, acc[1][1]);
      acc[1][2] = fmaf(a1, b2, acc[1][2]); acc[1][3] = fmaf(a1, b3, acc[1][3]);
      acc[2][0] = fmaf(a2, b0, acc[2][0]); acc[2][1] = fmaf(a2, b1, acc[2][1]);
      acc[2][2] = fmaf(a2, b2, acc[2][2]); acc[2][3] = fmaf(a2, b3, acc[2][3]);
      acc[3][0] = fmaf(a3, b0, acc[3][0]); acc[3][1] = fmaf(a3, b1, acc[3][1]);
      acc[3][2] = fmaf(a3, b2, acc[3][2]); acc[3][3] = fmaf(a3, b3, acc[3][3]);
    }
    __syncthreads();
  }
#pragma unroll
  for (int i = 0; i < 4; ++i)
#pragma unroll
    for (int j = 0; j < 4; ++j)
      C[(size_t)(bm + (ty << 2) + i) * N + bn + (tx << 2) + j] = acc[i][j];
}

// ---------------------------------------------------------------------------
// LSH sign hashes: one thread per (b,h,n); 8 dots of length 64 for q and k.
// qh/kh index: b*H*N + h*N + n, 8-bit code in a uint32.
// ---------------------------------------------------------------------------
__global__ __launch_bounds__(256) void hash_kernel(
    const float* __restrict__ q, const float* __restrict__ k,
    const float* __restrict__ rv,
    uint32_t* __restrict__ qh, uint32_t* __restrict__ kh) {
  __shared__ float rvs[8][DHh];
  for (int i = threadIdx.x; i < 8 * DHh; i += 256) rvs[i >> 6][i & 63] = rv[i];
  __syncthreads();
  const int idx = blockIdx.x * 256 + threadIdx.x;   // b*8192 + h*1024 + n
  const int n = idx & (Nn - 1);
  const int h = (idx >> 10) & (Hh - 1);
  const int b = idx >> 13;
  const float* __restrict__ qr = q + (size_t)(b * Nn + n) * DMm + h * DHh;
  const float* __restrict__ kr = k + (size_t)(b * Nn + n) * DMm + h * DHh;
  uint32_t qb = 0, kb = 0;
#pragma unroll
  for (int t = 0; t < 8; ++t) {
    float sq = 0.f, sk = 0.f;
#pragma unroll
    for (int d = 0; d < DHh; ++d) {
      float r = rvs[t][d];
      sq = fmaf(qr[d], r, sq);
      sk = fmaf(kr[d], r, sk);
    }
    qb |= (sq >= 0.f ? 1u : 0u) << t;
    kb |= (sk >= 0.f ? 1u : 0u) << t;
  }
  qh[idx] = qb;
  kh[idx] = kb;
}

// ---------------------------------------------------------------------------
// Per (b,h,n) row: top-102 by hash agreement (stable, ties -> lowest index,
// matching jax.lax.top_k), Poincare distance, softmax, weighted V.
// One 256-thread block per row; fully deterministic (ballot-scan placement).
// ---------------------------------------------------------------------------
__global__ __launch_bounds__(256) void attn_kernel(
    const float* __restrict__ q, const float* __restrict__ k,
    const float* __restrict__ v,
    const uint32_t* __restrict__ qh, const uint32_t* __restrict__ kh,
    float* __restrict__ out) {
  const int row  = blockIdx.x;            // b*H*N + h*N + n
  const int n    = row & (Nn - 1);
  const int h    = (row >> 10) & (Hh - 1);
  const int b    = row >> 13;
  const int tid  = threadIdx.x;
  const int lane = tid & 63;
  const int wid  = tid >> 6;

  __shared__ int   hist[9];
  __shared__ int   sel[TOPK];
  __shared__ float dist[TOPK];
  __shared__ float pw[TOPK];
  __shared__ float qs[DHh];
  __shared__ float oacc[4][DHh];
  __shared__ int   wsum_gt[4], wsum_eq[4];
  __shared__ int   thr_s, R_s, gt_s;
  __shared__ int   base_gt, base_eq;
  __shared__ float qn_s, mn_s, sum_s;

  if (tid < 9) hist[tid] = 0;
  if (tid == 0) { base_gt = 0; base_eq = 0; }
  const uint32_t myh = qh[row];
  const uint32_t* __restrict__ krh = kh + ((b * Hh + h) << 10);
  int mloc[4];
  __syncthreads();

  // 1) match counts + histogram (atomicAdd: order-independent sum)
#pragma unroll
  for (int it = 0; it < 4; ++it) {
    int j = tid + (it << 8);
    int m = 8 - __popc(myh ^ krh[j]);
    mloc[it] = m;
    atomicAdd(&hist[m], 1);
  }
  __syncthreads();

  // 2) threshold t and remainder R (thread 0)
  if (tid == 0) {
    int cum = 0, t = 0, R = TOPK;
    for (int mv = 8; mv >= 0; --mv) {
      int c = hist[mv];
      if (cum + c >= TOPK) { t = mv; R = TOPK - cum; break; }
      cum += c;
    }
    thr_s = t; R_s = R; gt_s = cum;
  }
  __syncthreads();
  const int thr = thr_s, Rr = R_s, gtc = gt_s;

  // 3) stable selection via block-wide ballot scan (deterministic slots)
  for (int it = 0; it < 4; ++it) {
    const int j  = tid + (it << 8);
    const bool gt = (mloc[it] > thr);
    const bool eq = (mloc[it] == thr);
    unsigned long long mg = __ballot(gt);
    unsigned long long me = __ballot(eq);
    if (lane == 0) { wsum_gt[wid] = __popcll(mg); wsum_eq[wid] = __popcll(me); }
    __syncthreads();
    const unsigned long long lt = (1ULL << lane) - 1ULL;
    int rg = base_gt + __popcll(mg & lt);
    int re = base_eq + __popcll(me & lt);
    for (int w = 0; w < wid; ++w) { rg += wsum_gt[w]; re += wsum_eq[w]; }
    if (gt) sel[rg] = j;
    if (eq && re < Rr) sel[gtc + re] = j;
    __syncthreads();
    if (tid == 0) {
      base_gt += wsum_gt[0] + wsum_gt[1] + wsum_gt[2] + wsum_gt[3];
      base_eq += wsum_eq[0] + wsum_eq[1] + wsum_eq[2] + wsum_eq[3];
    }
    __syncthreads();
  }

  // 4) stage q row, q norm
  if (tid < DHh) qs[tid] = q[(size_t)(b * Nn + n) * DMm + h * DHh + tid];
  __syncthreads();
  if (tid == 0) {
    float s = 0.f;
    for (int d = 0; d < DHh; ++d) s = fmaf(qs[d], qs[d], s);
    qn_s = s;
  }
  __syncthreads();
  const float oneq = 1.f - qn_s;

  // 5) Poincare distances for selected keys
  for (int s = tid; s < TOPK; s += 256) {
    const int j = sel[s];
    const float* __restrict__ kr = k + (size_t)(b * Nn + j) * DMm + h * DHh;
    float dsq = 0.f, knsq = 0.f;
#pragma unroll
    for (int d = 0; d < DHh; ++d) {
      float kd = kr[d];
      float df = qs[d] - kd;
      dsq  = fmaf(df, df, dsq);
      knsq = fmaf(kd, kd, knsq);
    }
    float denom = fmaxf(oneq * (1.f - knsq), 1e-6f);
    float carg  = fmaxf(1.f + 2.f * dsq / denom, 1.f);
    dist[s] = acoshf(carg);
  }
  __syncthreads();

  // 6) softmax(-dist): max(-d) = -min(d)
  if (tid == 0) {
    float mn = 3.4e38f;
    for (int s = 0; s < TOPK; ++s) mn = fminf(mn, dist[s]);
    mn_s = mn;
  }
  __syncthreads();
  for (int s = tid; s < TOPK; s += 256) pw[s] = expf(mn_s - dist[s]);
  __syncthreads();
  if (tid == 0) {
    float s2 = 0.f;
    for (int s = 0; s < TOPK; ++s) s2 += pw[s];
    sum_s = s2;
  }
  __syncthreads();

  // 7) out[d] = sum_s pw[s] * v[sel[s]][d] / sum   (4 partial strips + reduce)
  {
    const int d   = tid & 63;
    const int sub = tid >> 6;
    float acc = 0.f;
    for (int s = sub; s < TOPK; s += 4) {
      const float* __restrict__ vr = v + (size_t)(b * Nn + sel[s]) * DMm + h * DHh;
      acc = fmaf(pw[s], vr[d], acc);
    }
    oacc[sub][d] = acc;
  }
  __syncthreads();
  if (tid < DHh) {
    float r = (oacc[0][tid] + oacc[1][tid] + oacc[2][tid] + oacc[3][tid]) / sum_s;
    out[(size_t)(b * Nn + n) * DMm + h * DHh + tid] = r;
  }
}

// ---------------------------------------------------------------------------
extern "C" void kernel_launch(void* const* d_in, const int* in_sizes, int n_in,
                              void* d_out, int out_size, void* d_ws, size_t ws_size,
                              hipStream_t stream) {
  const float* x  = (const float*)d_in[0];
  const float* Wq = (const float*)d_in[1];
  const float* Wk = (const float*)d_in[2];
  const float* Wv = (const float*)d_in[3];
  const float* Wo = (const float*)d_in[4];
  const float* rv = (const float*)d_in[5];
  float* outp = (float*)d_out;

  const int M = Bb * Nn;  // 2048 rows
  float* q  = (float*)d_ws;
  float* k  = q + (size_t)M * DMm;
  float* v  = k + (size_t)M * DMm;
  float* ao = v + (size_t)M * DMm;
  uint32_t* qh = (uint32_t*)(ao + (size_t)M * DMm);
  uint32_t* kh = qh + (size_t)Bb * Hh * Nn;

  dim3 gg(M / 64, DMm / 64);   // 32 x 8 blocks
  gemm_nt64<<<gg, 256, 0, stream>>>(x, Wq, q, M, DMm, DMm);
  gemm_nt64<<<gg, 256, 0, stream>>>(x, Wk, k, M, DMm, DMm);
  gemm_nt64<<<gg, 256, 0, stream>>>(x, Wv, v, M, DMm, DMm);
  hash_kernel<<<(Bb * Hh * Nn) / 256, 256, 0, stream>>>(q, k, rv, qh, kh);
  attn_kernel<<<Bb * Hh * Nn, 256, 0, stream>>>(q, k, v, qh, kh, ao);
  gemm_nt64<<<gg, 256, 0, stream>>>(ao, Wo, outp, M, DMm, DMm);
}

// Round 2
// 310.627 us; speedup vs baseline: 1.0977x; 1.0977x over previous
//
#include <hip/hip_runtime.h>
#include <cstdint>
#include <cstddef>

#define Bb   2
#define Nn   1024
#define Hh   8
#define DHh  64
#define DMm  512
#define TOPK 102   // int(1024 * (1.0 - 0.9)) == 102

// ---------------------------------------------------------------------------
// C[M,N] = A[M,K] @ B[N,K]^T   (both row-major, inner dim K) — f32 vector FMA
// 64x64 tile, BK=16, 256 threads, 4x4 micro-tile per thread.
// ---------------------------------------------------------------------------
__global__ __launch_bounds__(256) void gemm_nt64(
    const float* __restrict__ A, const float* __restrict__ Bm,
    float* __restrict__ C, int M, int N, int K) {
  __shared__ float As[64][17];
  __shared__ float Bs[64][17];
  const int tid = threadIdx.x;
  const int tx  = tid & 15;
  const int ty  = tid >> 4;
  const int bm  = blockIdx.x << 6;
  const int bn  = blockIdx.y << 6;
  float acc[4][4] = {};
  for (int k0 = 0; k0 < K; k0 += 16) {
#pragma unroll
    for (int i = 0; i < 4; ++i) {
      int e = tid + (i << 8);          // 0..1023
      int r = e >> 4, c = e & 15;
      As[r][c] = A[(size_t)(bm + r) * K + k0 + c];
      Bs[r][c] = Bm[(size_t)(bn + r) * K + k0 + c];
    }
    __syncthreads();
#pragma unroll
    for (int kk = 0; kk < 16; ++kk) {
      float a0 = As[(ty << 2) + 0][kk], a1 = As[(ty << 2) + 1][kk];
      float a2 = As[(ty << 2) + 2][kk], a3 = As[(ty << 2) + 3][kk];
      float b0 = Bs[(tx << 2) + 0][kk], b1 = Bs[(tx << 2) + 1][kk];
      float b2 = Bs[(tx << 2) + 2][kk], b3 = Bs[(tx << 2) + 3][kk];
      acc[0][0] = fmaf(a0, b0, acc[0][0]); acc[0][1] = fmaf(a0, b1, acc[0][1]);
      acc[0][2] = fmaf(a0, b2, acc[0][2]); acc[0][3] = fmaf(a0, b3, acc[0][3]);
      acc[1][0] = fmaf(a1, b0, acc[1][0]); acc[1][1] = fmaf(a1, b1, acc[1][1]);
      acc[1][2] = fmaf(a1, b2, acc[1][2]); acc[1][3] = fmaf(a1, b3, acc[1][3]);
      acc[2][0] = fmaf(a2, b0, acc[2][0]); acc[2][1] = fmaf(a2, b1, acc[2][1]);
      acc[2][2] = fmaf(a2, b2, acc[2][2]); acc[2][3] = fmaf(a2, b3, acc[2][3]);
      acc[3][0] = fmaf(a3, b0, acc[3][0]); acc[3][1] = fmaf(a3, b1, acc[3][1]);
      acc[3][2] = fmaf(a3, b2, acc[3][2]); acc[3][3] = fmaf(a3, b3, acc[3][3]);
    }
    __syncthreads();
  }
#pragma unroll
  for (int i = 0; i < 4; ++i)
#pragma unroll
    for (int j = 0; j < 4; ++j)
      C[(size_t)(bm + (ty << 2) + i) * N + bn + (tx << 2) + j] = acc[i][j];
}

// ---------------------------------------------------------------------------
// Hash + norms: one wave per (b,h,n) row. lane = head-dim d.
// Outputs: 8-bit sign codes qh/kh, squared norms qn/kn (per row).
// Butterfly shuffle reduce; zero barriers.
// ---------------------------------------------------------------------------
__global__ __launch_bounds__(256) void hash_norm_kernel(
    const float* __restrict__ q, const float* __restrict__ k,
    const float* __restrict__ rv,
    uint32_t* __restrict__ qh, uint32_t* __restrict__ kh,
    float* __restrict__ qn, float* __restrict__ kn) {
  const int wid  = threadIdx.x >> 6;
  const int lane = threadIdx.x & 63;
  const int row  = blockIdx.x * 4 + wid;      // b*H*N + h*N + n
  const int n    = row & (Nn - 1);
  const int bh   = row >> 10;
  const int b    = bh >> 3, h = bh & 7;
  const size_t off = (size_t)(b * Nn + n) * DMm + h * DHh + lane;
  const float qd = q[off], kd = k[off];
  float acc[18];
#pragma unroll
  for (int t = 0; t < 8; ++t) {
    float r = rv[t * DHh + lane];
    acc[t]     = qd * r;
    acc[8 + t] = kd * r;
  }
  acc[16] = qd * qd;
  acc[17] = kd * kd;
#pragma unroll
  for (int i = 0; i < 18; ++i) {
#pragma unroll
    for (int s = 1; s < 64; s <<= 1) acc[i] += __shfl_xor(acc[i], s);
  }
  if (lane == 0) {
    uint32_t qb = 0, kb = 0;
#pragma unroll
    for (int t = 0; t < 8; ++t) {
      qb |= (acc[t]     >= 0.f ? 1u : 0u) << t;
      kb |= (acc[8 + t] >= 0.f ? 1u : 0u) << t;
    }
    qh[row] = qb; kh[row] = kb;
    qn[row] = acc[16]; kn[row] = acc[17];
  }
}

// ---------------------------------------------------------------------------
// Attention: one wave per (b,h,n) row. Zero __syncthreads.
//  1) 16 kh codes/lane -> match counts
//  2) packed-byte per-lane histogram -> butterfly reduce -> uniform threshold
//  3) stable top-102 via per-chunk ballot prefix scan (ties -> lowest index)
//  4) distance = acosh(max(1 + 2*dsq/denom,1)), dsq = qn + kn - 2*q.k
//     4 keys/iter: 4 groups x 16 lanes, coalesced float4 k loads
//  5) wave softmax (shuffle min / sum)
//  6) PV with same 4-group layout, coalesced float4 v loads + stores
// ---------------------------------------------------------------------------
__global__ __launch_bounds__(256) void attn_wave_kernel(
    const float* __restrict__ q, const float* __restrict__ k,
    const float* __restrict__ v,
    const uint32_t* __restrict__ qh, const uint32_t* __restrict__ kh,
    const float* __restrict__ qn, const float* __restrict__ kn,
    float* __restrict__ out) {
  const int wid  = threadIdx.x >> 6;
  const int lane = threadIdx.x & 63;
  const int row  = blockIdx.x * 4 + wid;      // b*H*N + h*N + n
  const int n    = row & (Nn - 1);
  const int bh   = row >> 10;
  const int b    = bh >> 3, h = bh & 7;

  __shared__ float qs[4][DHh];
  __shared__ int   sel[4][TOPK];
  __shared__ float dw[4][TOPK + 2];

  const uint32_t myh = qh[row];
  const uint32_t* __restrict__ krh = kh + (bh << 10);

  // 1) match counts: 16 keys per lane, key j = c*64 + lane
  int m[16];
#pragma unroll
  for (int c = 0; c < 16; ++c)
    m[c] = 8 - __popc(myh ^ krh[(c << 6) + lane]);

  // 2) histogram of 9 bins, packed bytes locally then butterfly reduce
  uint32_t p0 = 0, p1 = 0, p2 = 0;
#pragma unroll
  for (int c = 0; c < 16; ++c) {
    uint32_t one = 1u << ((m[c] & 3) << 3);
    int g = m[c] >> 2;
    p0 += (g == 0) ? one : 0u;
    p1 += (g == 1) ? one : 0u;
    p2 += (g == 2) ? one : 0u;
  }
  int cnt[9];
#pragma unroll
  for (int i = 0; i < 4; ++i) cnt[i]     = (p0 >> (i * 8)) & 0xff;
#pragma unroll
  for (int i = 0; i < 4; ++i) cnt[4 + i] = (p1 >> (i * 8)) & 0xff;
  cnt[8] = p2 & 0xff;
#pragma unroll
  for (int i = 0; i < 9; ++i) {
#pragma unroll
    for (int s = 1; s < 64; s <<= 1) cnt[i] += __shfl_xor(cnt[i], s);
  }

  // threshold scan (uniform on all lanes)
  int thr = 0, R = TOPK, gtc = 0;
  {
    int cum = 0; bool done = false;
#pragma unroll
    for (int mv = 8; mv >= 0; --mv) {
      int c = cnt[mv];
      if (!done && cum + c >= TOPK) { thr = mv; R = TOPK - cum; gtc = cum; done = true; }
      if (!done) cum += c;
    }
  }

  // 3) stable selection: ballot prefix scan per chunk
  const unsigned long long ltm = (1ULL << lane) - 1ULL;
  int bgt = 0, beq = 0;
#pragma unroll
  for (int c = 0; c < 16; ++c) {
    bool gt = m[c] > thr, eq = m[c] == thr;
    unsigned long long mg = __ballot(gt);
    unsigned long long me = __ballot(eq);
    int rg = bgt + __popcll(mg & ltm);
    int re = beq + __popcll(me & ltm);
    int j = (c << 6) + lane;
    if (gt) sel[wid][rg] = j;
    else if (eq && re < R) sel[wid][gtc + re] = j;
    bgt += __popcll(mg);
    beq += __popcll(me);
  }

  // 4) stage q row in LDS, distances for selected keys
  if (lane < 16) {
    const float4 qv = *(const float4*)(q + (size_t)(b * Nn + n) * DMm + h * DHh + lane * 4);
    *(float4*)&qs[wid][lane * 4] = qv;
  }
  const float qnrm = qn[row];
  const float oneq = 1.f - qnrm;

  const int g  = lane >> 4;   // group 0..3 (one key each per iter)
  const int gl = lane & 15;   // 4 dims each
  const float* __restrict__ kbh = k + (size_t)b * Nn * DMm + h * DHh;
  const float* __restrict__ knb = kn + (bh << 10);

  for (int it = 0; it < 26; ++it) {
    int s = it * 4 + g;
    bool act = s < TOPK;
    int j = act ? sel[wid][s] : sel[wid][0];
    float4 kv = *(const float4*)(kbh + (size_t)j * DMm + gl * 4);
    float4 qv = *(const float4*)&qs[wid][gl * 4];
    float dot = kv.x * qv.x + kv.y * qv.y + kv.z * qv.z + kv.w * qv.w;
    dot += __shfl_xor(dot, 1);
    dot += __shfl_xor(dot, 2);
    dot += __shfl_xor(dot, 4);
    dot += __shfl_xor(dot, 8);
    if (gl == 0 && act) {
      float knj  = knb[j];
      float dsq  = fmaxf(qnrm + knj - 2.f * dot, 0.f);
      float den  = fmaxf(oneq * (1.f - knj), 1e-6f);
      float carg = fmaxf(1.f + 2.f * dsq / den, 1.f);
      dw[wid][s] = acoshf(carg);
    }
  }

  // 5) softmax(-dist) across 102 slots: lane covers s=lane and s=lane+64
  float d0 = dw[wid][lane];
  float d1 = (lane + 64 < TOPK) ? dw[wid][lane + 64] : 3.4e38f;
  float mn = fminf(d0, d1);
#pragma unroll
  for (int s = 1; s < 64; s <<= 1) mn = fminf(mn, __shfl_xor(mn, s));
  float e0 = expf(mn - d0);
  float e1 = (lane + 64 < TOPK) ? expf(mn - d1) : 0.f;
  dw[wid][lane] = e0;
  if (lane + 64 < TOPK) dw[wid][lane + 64] = e1;
  float sm = e0 + e1;
#pragma unroll
  for (int s = 1; s < 64; s <<= 1) sm += __shfl_xor(sm, s);
  const float inv = 1.f / sm;

  // 6) PV: 4-group accumulation, cross-group shuffle reduce, float4 store
  const float* __restrict__ vbh = v + (size_t)b * Nn * DMm + h * DHh;
  float4 oa = {0.f, 0.f, 0.f, 0.f};
  for (int it = 0; it < 26; ++it) {
    int s = it * 4 + g;
    if (s < TOPK) {
      int j   = sel[wid][s];
      float w = dw[wid][s];
      float4 vv = *(const float4*)(vbh + (size_t)j * DMm + gl * 4);
      oa.x = fmaf(w, vv.x, oa.x);
      oa.y = fmaf(w, vv.y, oa.y);
      oa.z = fmaf(w, vv.z, oa.z);
      oa.w = fmaf(w, vv.w, oa.w);
    }
  }
#pragma unroll
  for (int s = 16; s < 64; s <<= 1) {
    oa.x += __shfl_xor(oa.x, s);
    oa.y += __shfl_xor(oa.y, s);
    oa.z += __shfl_xor(oa.z, s);
    oa.w += __shfl_xor(oa.w, s);
  }
  if (lane < 16) {
    float4 r;
    r.x = oa.x * inv; r.y = oa.y * inv; r.z = oa.z * inv; r.w = oa.w * inv;
    *(float4*)(out + (size_t)(b * Nn + n) * DMm + h * DHh + lane * 4) = r;
  }
}

// ---------------------------------------------------------------------------
extern "C" void kernel_launch(void* const* d_in, const int* in_sizes, int n_in,
                              void* d_out, int out_size, void* d_ws, size_t ws_size,
                              hipStream_t stream) {
  const float* x  = (const float*)d_in[0];
  const float* Wq = (const float*)d_in[1];
  const float* Wk = (const float*)d_in[2];
  const float* Wv = (const float*)d_in[3];
  const float* Wo = (const float*)d_in[4];
  const float* rv = (const float*)d_in[5];
  float* outp = (float*)d_out;

  const int M = Bb * Nn;      // 2048 rows
  const int RWS = Bb * Hh * Nn;  // 16384 (b,h,n) rows
  float* q  = (float*)d_ws;
  float* k  = q + (size_t)M * DMm;
  float* v  = k + (size_t)M * DMm;
  float* ao = v + (size_t)M * DMm;
  uint32_t* qh = (uint32_t*)(ao + (size_t)M * DMm);
  uint32_t* kh = qh + RWS;
  float* qn = (float*)(kh + RWS);
  float* kn = qn + RWS;

  dim3 gg(M / 64, DMm / 64);   // 32 x 8 blocks
  gemm_nt64<<<gg, 256, 0, stream>>>(x, Wq, q, M, DMm, DMm);
  gemm_nt64<<<gg, 256, 0, stream>>>(x, Wk, k, M, DMm, DMm);
  gemm_nt64<<<gg, 256, 0, stream>>>(x, Wv, v, M, DMm, DMm);
  hash_norm_kernel<<<RWS / 4, 256, 0, stream>>>(q, k, rv, qh, kh, qn, kn);
  attn_wave_kernel<<<RWS / 4, 256, 0, stream>>>(q, k, v, qh, kh, qn, kn, ao);
  gemm_nt64<<<gg, 256, 0, stream>>>(ao, Wo, outp, M, DMm, DMm);
}

// Round 3
// 222.321 us; speedup vs baseline: 1.5337x; 1.3972x over previous
//
#include <hip/hip_runtime.h>
#include <cstdint>
#include <cstddef>

#define Bb   2
#define Nn   1024
#define Hh   8
#define DHh  64
#define DMm  512
#define TOPK 102   // int(1024 * (1.0 - 0.9)) == 102

// ---------------------------------------------------------------------------
// C[M,N] = A[M,K] @ B[N,K]^T   (both row-major, inner dim K) — f32 vector FMA
// 64x64 tile, BK=16, 256 threads, 4x4 micro-tile per thread.
// ---------------------------------------------------------------------------
__global__ __launch_bounds__(256) void gemm_nt64(
    const float* __restrict__ A, const float* __restrict__ Bm,
    float* __restrict__ C, int M, int N, int K) {
  __shared__ float As[64][17];
  __shared__ float Bs[64][17];
  const int tid = threadIdx.x;
  const int tx  = tid & 15;
  const int ty  = tid >> 4;
  const int bm  = blockIdx.x << 6;
  const int bn  = blockIdx.y << 6;
  float acc[4][4] = {};
  for (int k0 = 0; k0 < K; k0 += 16) {
#pragma unroll
    for (int i = 0; i < 4; ++i) {
      int e = tid + (i << 8);          // 0..1023
      int r = e >> 4, c = e & 15;
      As[r][c] = A[(size_t)(bm + r) * K + k0 + c];
      Bs[r][c] = Bm[(size_t)(bn + r) * K + k0 + c];
    }
    __syncthreads();
#pragma unroll
    for (int kk = 0; kk < 16; ++kk) {
      float a0 = As[(ty << 2) + 0][kk], a1 = As[(ty << 2) + 1][kk];
      float a2 = As[(ty << 2) + 2][kk], a3 = As[(ty << 2) + 3][kk];
      float b0 = Bs[(tx << 2) + 0][kk], b1 = Bs[(tx << 2) + 1][kk];
      float b2 = Bs[(tx << 2) + 2][kk], b3 = Bs[(tx << 2) + 3][kk];
      acc[0][0] = fmaf(a0, b0, acc[0][0]); acc[0][1] = fmaf(a0, b1, acc[0][1]);
      acc[0][2] = fmaf(a0, b2, acc[0][2]); acc[0][3] = fmaf(a0, b3, acc[0][3]);
      acc[1][0] = fmaf(a1, b0, acc[1][0]); acc[1][1] = fmaf(a1, b1, acc[1][1]);
      acc[1][2] = fmaf(a1, b2, acc[1][2]); acc[1][3] = fmaf(a1, b3, acc[1][3]);
      acc[2][0] = fmaf(a2, b0, acc[2][0]); acc[2][1] = fmaf(a2, b1, acc[2][1]);
      acc[2][2] = fmaf(a2, b2, acc[2][2]); acc[2][3] = fmaf(a2, b3, acc[2][3]);
      acc[3][0] = fmaf(a3, b0, acc[3][0]); acc[3][1] = fmaf(a3, b1, acc[3][1]);
      acc[3][2] = fmaf(a3, b2, acc[3][2]); acc[3][3] = fmaf(a3, b3, acc[3][3]);
    }
    __syncthreads();
  }
#pragma unroll
  for (int i = 0; i < 4; ++i)
#pragma unroll
    for (int j = 0; j < 4; ++j)
      C[(size_t)(bm + (ty << 2) + i) * N + bn + (tx << 2) + j] = acc[i][j];
}

// ---------------------------------------------------------------------------
// Hash + norms: one wave per (b,h,n) row. lane = head-dim d.
// ---------------------------------------------------------------------------
__global__ __launch_bounds__(256) void hash_norm_kernel(
    const float* __restrict__ q, const float* __restrict__ k,
    const float* __restrict__ rv,
    uint32_t* __restrict__ qh, uint32_t* __restrict__ kh,
    float* __restrict__ qn, float* __restrict__ kn) {
  const int wid  = threadIdx.x >> 6;
  const int lane = threadIdx.x & 63;
  const int row  = blockIdx.x * 4 + wid;      // b*H*N + h*N + n
  const int n    = row & (Nn - 1);
  const int bh   = row >> 10;
  const int b    = bh >> 3, h = bh & 7;
  const size_t off = (size_t)(b * Nn + n) * DMm + h * DHh + lane;
  const float qd = q[off], kd = k[off];
  float acc[18];
#pragma unroll
  for (int t = 0; t < 8; ++t) {
    float r = rv[t * DHh + lane];
    acc[t]     = qd * r;
    acc[8 + t] = kd * r;
  }
  acc[16] = qd * qd;
  acc[17] = kd * kd;
#pragma unroll
  for (int i = 0; i < 18; ++i) {
#pragma unroll
    for (int s = 1; s < 64; s <<= 1) acc[i] += __shfl_xor(acc[i], s);
  }
  if (lane == 0) {
    uint32_t qb = 0, kb = 0;
#pragma unroll
    for (int t = 0; t < 8; ++t) {
      qb |= (acc[t]     >= 0.f ? 1u : 0u) << t;
      kb |= (acc[8 + t] >= 0.f ? 1u : 0u) << t;
    }
    qh[row] = qb; kh[row] = kb;
    qn[row] = acc[16]; kn[row] = acc[17];
  }
}

// ---------------------------------------------------------------------------
// Attention: one wave per (b,h,n) row, zero block barriers.
// softmax(-acosh(c)) == (1/z)/sum(1/z) with z = c + sqrt(c^2-1): no acosh/exp.
// 8 groups x 8 lanes: 8 keys/iter for dot & PV; batched weight pass.
// ---------------------------------------------------------------------------
__global__ __launch_bounds__(256) void attn_wave_kernel(
    const float* __restrict__ q, const float* __restrict__ k,
    const float* __restrict__ v,
    const uint32_t* __restrict__ qh, const uint32_t* __restrict__ kh,
    const float* __restrict__ qn, const float* __restrict__ kn,
    float* __restrict__ out) {
  const int wid  = threadIdx.x >> 6;
  const int lane = threadIdx.x & 63;
  const int row  = blockIdx.x * 4 + wid;      // b*H*N + h*N + n
  const int n    = row & (Nn - 1);
  const int bh   = row >> 10;
  const int b    = bh >> 3, h = bh & 7;

  __shared__ int   sel[4][104];
  __shared__ float dw[4][104];

  const uint32_t myh = qh[row];
  const uint32_t* __restrict__ krh = kh + (bh << 10);

  // 1) match counts: 16 keys per lane, key j = c*64 + lane
  int m[16];
#pragma unroll
  for (int c = 0; c < 16; ++c)
    m[c] = 8 - __popc(myh ^ krh[(c << 6) + lane]);

  // 2) 9-bin histogram: per-lane byte packing, then 16-bit-field reduce
  uint32_t p0 = 0, p1 = 0, p2 = 0;
#pragma unroll
  for (int c = 0; c < 16; ++c) {
    uint32_t one = 1u << ((m[c] & 3) << 3);
    int gq = m[c] >> 2;
    p0 += (gq == 0) ? one : 0u;
    p1 += (gq == 1) ? one : 0u;
    p2 += (gq == 2) ? one : 0u;
  }
  uint32_t hr[5];
  hr[0] = (p0 & 0xffu) | (((p0 >> 8) & 0xffu) << 16);
  hr[1] = ((p0 >> 16) & 0xffu) | (((p0 >> 24) & 0xffu) << 16);
  hr[2] = (p1 & 0xffu) | (((p1 >> 8) & 0xffu) << 16);
  hr[3] = ((p1 >> 16) & 0xffu) | (((p1 >> 24) & 0xffu) << 16);
  hr[4] = p2 & 0xffu;
#pragma unroll
  for (int i = 0; i < 5; ++i) {
#pragma unroll
    for (int s = 1; s < 64; s <<= 1) hr[i] += __shfl_xor(hr[i], s);
  }
  int cnt[9];
#pragma unroll
  for (int i = 0; i < 4; ++i) {
    cnt[2 * i]     = hr[i] & 0xffffu;
    cnt[2 * i + 1] = hr[i] >> 16;
  }
  cnt[8] = hr[4] & 0xffffu;

  // threshold scan (uniform on all lanes)
  int thr = 0, R = TOPK, gtc = 0;
  {
    int cum = 0; bool done = false;
#pragma unroll
    for (int mv = 8; mv >= 0; --mv) {
      int c = cnt[mv];
      if (!done && cum + c >= TOPK) { thr = mv; R = TOPK - cum; gtc = cum; done = true; }
      if (!done) cum += c;
    }
  }

  // 3) stable selection (ties -> lowest index): ballot prefix scan per chunk
  const unsigned long long ltm = (1ULL << lane) - 1ULL;
  int bgt = 0, beq = 0;
#pragma unroll
  for (int c = 0; c < 16; ++c) {
    bool gt = m[c] > thr, eq = m[c] == thr;
    unsigned long long mg = __ballot(gt);
    unsigned long long me = __ballot(eq);
    int rg = bgt + __popcll(mg & ltm);
    int re = beq + __popcll(me & ltm);
    int j = (c << 6) + lane;
    if (gt) sel[wid][rg] = j;
    else if (eq && re < R) sel[wid][gtc + re] = j;
    bgt += __popcll(mg);
    beq += __popcll(me);
  }
  __builtin_amdgcn_wave_barrier();

  // 4) q row in registers: group g handles key s=it*8+g, lane gl owns dims gl*8..+7
  const int g  = lane >> 3;
  const int gl = lane & 7;
  const float* __restrict__ qrow = q + (size_t)(b * Nn + n) * DMm + h * DHh + gl * 8;
  const float4 qv0 = *(const float4*)qrow;
  const float4 qv1 = *(const float4*)(qrow + 4);
  const float qnrm = qn[row];
  const float oneq = 1.f - qnrm;
  const float* __restrict__ kbh = k + (size_t)b * Nn * DMm + h * DHh;
  const float* __restrict__ knb = kn + (bh << 10);

  // Phase A: dot products, 8 keys per iteration
#pragma unroll
  for (int it = 0; it < 13; ++it) {
    int s = it * 8 + g;
    bool act = s < TOPK;
    int j = act ? sel[wid][s] : sel[wid][0];
    const float* __restrict__ kr = kbh + (size_t)j * DMm + gl * 8;
    float4 kv0 = *(const float4*)kr;
    float4 kv1 = *(const float4*)(kr + 4);
    float dot = kv0.x * qv0.x;
    dot = fmaf(kv0.y, qv0.y, dot);
    dot = fmaf(kv0.z, qv0.z, dot);
    dot = fmaf(kv0.w, qv0.w, dot);
    dot = fmaf(kv1.x, qv1.x, dot);
    dot = fmaf(kv1.y, qv1.y, dot);
    dot = fmaf(kv1.z, qv1.z, dot);
    dot = fmaf(kv1.w, qv1.w, dot);
    dot += __shfl_xor(dot, 1);
    dot += __shfl_xor(dot, 2);
    dot += __shfl_xor(dot, 4);
    if (gl == 0 && act) dw[wid][s] = dot;
  }
  __builtin_amdgcn_wave_barrier();

  // Phase B: batched weights w = 1/(c + sqrt(c^2-1)), 2 keys per lane
  float w0, w1 = 0.f;
  {
    int j0 = sel[wid][lane];
    float dot0 = dw[wid][lane];
    float kn0 = knb[j0];
    float dsq = fmaxf(qnrm + kn0 - 2.f * dot0, 0.f);
    float den = fmaxf(oneq * (1.f - kn0), 1e-6f);
    float c   = fmaxf(fmaf(2.f * dsq, __builtin_amdgcn_rcpf(den), 1.f), 1.f);
    float z   = c + __builtin_amdgcn_sqrtf(fmaf(c, c, -1.f));
    w0 = __builtin_amdgcn_rcpf(z);
  }
  if (lane + 64 < TOPK) {
    int j1 = sel[wid][lane + 64];
    float dot1 = dw[wid][lane + 64];
    float kn1 = knb[j1];
    float dsq = fmaxf(qnrm + kn1 - 2.f * dot1, 0.f);
    float den = fmaxf(oneq * (1.f - kn1), 1e-6f);
    float c   = fmaxf(fmaf(2.f * dsq, __builtin_amdgcn_rcpf(den), 1.f), 1.f);
    float z   = c + __builtin_amdgcn_sqrtf(fmaf(c, c, -1.f));
    w1 = __builtin_amdgcn_rcpf(z);
  }
  float sm = w0 + w1;
#pragma unroll
  for (int s = 1; s < 64; s <<= 1) sm += __shfl_xor(sm, s);
  const float inv = __builtin_amdgcn_rcpf(sm);
  dw[wid][lane] = w0;
  if (lane + 64 < TOPK) dw[wid][lane + 64] = w1;
  __builtin_amdgcn_wave_barrier();

  // Phase C: PV, 8 keys per iteration, then 3-step cross-group reduce
  const float* __restrict__ vbh = v + (size_t)b * Nn * DMm + h * DHh;
  float4 oa0 = {0.f, 0.f, 0.f, 0.f};
  float4 oa1 = {0.f, 0.f, 0.f, 0.f};
#pragma unroll
  for (int it = 0; it < 13; ++it) {
    int s = it * 8 + g;
    if (s < TOPK) {
      int j   = sel[wid][s];
      float w = dw[wid][s];
      const float* __restrict__ vr = vbh + (size_t)j * DMm + gl * 8;
      float4 v0 = *(const float4*)vr;
      float4 v1 = *(const float4*)(vr + 4);
      oa0.x = fmaf(w, v0.x, oa0.x); oa0.y = fmaf(w, v0.y, oa0.y);
      oa0.z = fmaf(w, v0.z, oa0.z); oa0.w = fmaf(w, v0.w, oa0.w);
      oa1.x = fmaf(w, v1.x, oa1.x); oa1.y = fmaf(w, v1.y, oa1.y);
      oa1.z = fmaf(w, v1.z, oa1.z); oa1.w = fmaf(w, v1.w, oa1.w);
    }
  }
#pragma unroll
  for (int s = 8; s < 64; s <<= 1) {
    oa0.x += __shfl_xor(oa0.x, s); oa0.y += __shfl_xor(oa0.y, s);
    oa0.z += __shfl_xor(oa0.z, s); oa0.w += __shfl_xor(oa0.w, s);
    oa1.x += __shfl_xor(oa1.x, s); oa1.y += __shfl_xor(oa1.y, s);
    oa1.z += __shfl_xor(oa1.z, s); oa1.w += __shfl_xor(oa1.w, s);
  }
  if (g == 0) {
    float* __restrict__ orow = out + (size_t)(b * Nn + n) * DMm + h * DHh + gl * 8;
    float4 r0, r1;
    r0.x = oa0.x * inv; r0.y = oa0.y * inv; r0.z = oa0.z * inv; r0.w = oa0.w * inv;
    r1.x = oa1.x * inv; r1.y = oa1.y * inv; r1.z = oa1.z * inv; r1.w = oa1.w * inv;
    *(float4*)orow = r0;
    *(float4*)(orow + 4) = r1;
  }
}

// ---------------------------------------------------------------------------
extern "C" void kernel_launch(void* const* d_in, const int* in_sizes, int n_in,
                              void* d_out, int out_size, void* d_ws, size_t ws_size,
                              hipStream_t stream) {
  const float* x  = (const float*)d_in[0];
  const float* Wq = (const float*)d_in[1];
  const float* Wk = (const float*)d_in[2];
  const float* Wv = (const float*)d_in[3];
  const float* Wo = (const float*)d_in[4];
  const float* rv = (const float*)d_in[5];
  float* outp = (float*)d_out;

  const int M = Bb * Nn;         // 2048 rows
  const int RWS = Bb * Hh * Nn;  // 16384 (b,h,n) rows
  float* q  = (float*)d_ws;
  float* k  = q + (size_t)M * DMm;
  float* v  = k + (size_t)M * DMm;
  float* ao = v + (size_t)M * DMm;
  uint32_t* qh = (uint32_t*)(ao + (size_t)M * DMm);
  uint32_t* kh = qh + RWS;
  float* qn = (float*)(kh + RWS);
  float* kn = qn + RWS;

  dim3 gg(M / 64, DMm / 64);   // 32 x 8 blocks
  gemm_nt64<<<gg, 256, 0, stream>>>(x, Wq, q, M, DMm, DMm);
  gemm_nt64<<<gg, 256, 0, stream>>>(x, Wk, k, M, DMm, DMm);
  gemm_nt64<<<gg, 256, 0, stream>>>(x, Wv, v, M, DMm, DMm);
  hash_norm_kernel<<<RWS / 4, 256, 0, stream>>>(q, k, rv, qh, kh, qn, kn);
  attn_wave_kernel<<<RWS / 4, 256, 0, stream>>>(q, k, v, qh, kh, qn, kn, ao);
  gemm_nt64<<<gg, 256, 0, stream>>>(ao, Wo, outp, M, DMm, DMm);
}